// Round 5
// baseline (580.228 us; speedup 1.0000x reference)
//
#include <hip/hip_runtime.h>

// Problem constants
#define B_    32
#define T_    512
#define TT    (T_ * T_)        // 262144
#define NCELL (B_ * TT)        // 8388608
#define NBINS 4096
#define CAP   8192

// Workspace layout (bytes) — total need: 6 MiB
#define OFF_HIST   0                            // int hist[2][32][4096]  = 1 MiB
#define OFF_NFG    (2 * B_ * NBINS * 4)         // float nfg_sum[32]
#define OFF_GCNT   (OFF_NFG + B_ * 4)           // int gcnt[64]
#define OFF_BB     (OFF_GCNT + 64 * 4)          // int bb[64]
#define OFF_RSEL   (OFF_BB + 64 * 4)            // int rsel[64]
#define OFF_THR    (OFF_RSEL + 64 * 4)          // u64 thr[64] (8B aligned)
#define ZERO_BYTES (OFF_THR + 64 * 8)
#define OFF_GBUF   (2u * 1024 * 1024)           // u64 gbuf[64][CAP] = 4 MiB
// rec[NCELL] (packed flag|u_bits, 32 MiB) lives in d_out's anchor region:
// written by K1, read by K3, read+overwritten in place by K5.

// K1: full pass — coords, pos_valid, rec pack, histograms, fg-sum
__global__ __launch_bounds__(256) void k1_main(
    const float* __restrict__ gt, const float* __restrict__ alli,
    const float* __restrict__ ufg, const float* __restrict__ ubg,
    float* __restrict__ coords, float* __restrict__ posv,
    unsigned* __restrict__ rec, int* __restrict__ hist,
    float* __restrict__ nfg_sum)
{
    int g  = blockIdx.x * blockDim.x + threadIdx.x;
    int i0 = g << 2;                       // 4 cells per thread
    int b   = i0 >> 18;                    // / TT
    int rem = i0 & (TT - 1);
    int d   = rem >> 9;                    // / T
    int s   = rem & (T_ - 1);

    float4 gv = *reinterpret_cast<const float4*>(gt   + i0);
    float4 av = *reinterpret_cast<const float4*>(alli + i0);
    float4 fv = *reinterpret_cast<const float4*>(ufg  + i0);
    float4 bv = *reinterpret_cast<const float4*>(ubg  + i0);

    // coords rows: [b, s, s+d+1] for 4 consecutive s
    float fb = (float)b, fs = (float)s, fe = (float)(s + d + 1);
    float4 c0 = make_float4(fb,        fs,        fe,        fb);
    float4 c1 = make_float4(fs + 1.f,  fe + 1.f,  fb,        fs + 2.f);
    float4 c2 = make_float4(fe + 2.f,  fb,        fs + 3.f,  fe + 3.f);
    float4* cp = reinterpret_cast<float4*>(coords + (size_t)i0 * 3);
    cp[0] = c0; cp[1] = c1; cp[2] = c2;

    float4 pv;
    uint4  rv;
    float  fgsum = 0.f;
    #pragma unroll
    for (int j = 0; j < 4; ++j) {
        float gtv = ((const float*)&gv)[j];
        float al  = ((const float*)&av)[j];
        bool  fgc   = (gtv > 0.5f);
        float fgval = fgc ? al : 0.f;
        fgsum += fgval;
        bool fg = fgval > 0.f;
        bool bg = (!fgc) && (al > 0.f);
        ((float*)&pv)[j] = (fgc && al >= 1.f) ? 1.f : 0.f;
        unsigned flag = fg ? 1u : (bg ? 2u : 0u);
        unsigned out  = 0u;
        if (flag) {
            float u = (flag == 1u) ? ((const float*)&fv)[j] : ((const float*)&bv)[j];
            unsigned ub = __float_as_uint(u);      // u in [0,1) -> fits 30 bits
            out = (flag << 30) | ub;
            int bin = (int)(u * 4096.f);
            bin = bin > (NBINS - 1) ? (NBINS - 1) : bin;
            atomicAdd(hist + (((int)flag - 1) * B_ + b) * NBINS + bin, 1);
        }
        ((unsigned*)&rv)[j] = out;
    }
    *reinterpret_cast<float4*>(posv + i0) = pv;
    *reinterpret_cast<uint4*>(rec + i0)   = rv;

    // fg-mask value sum: wave reduce, then block reduce, one atomic per block.
    // Block = 1024 consecutive cells -> single batch (TT % 1024 == 0).
    for (int off = 32; off; off >>= 1) fgsum += __shfl_down(fgsum, off);
    __shared__ float red[4];
    int lane = threadIdx.x & 63, w = threadIdx.x >> 6;
    if (lane == 0) red[w] = fgsum;
    __syncthreads();
    if (threadIdx.x == 0) {
        float t = red[0] + red[1] + red[2] + red[3];
        if (t != 0.f) atomicAdd(nfg_sum + b, t);
    }
}

// K2: per (which,b) find boundary bin + rank within bin
__global__ __launch_bounds__(256) void k2_bounds(
    const int* __restrict__ hist, const float* __restrict__ nfg_sum,
    int* __restrict__ bb, int* __restrict__ rsel)
{
    int wb = blockIdx.x;              // 0..63: which*32 + b
    int which = wb >> 5, b = wb & 31;
    const int* h = hist + wb * NBINS;
    int t = threadIdx.x;
    int base = t * 16;
    int mybins[16];
    int loc = 0;
    #pragma unroll
    for (int j = 0; j < 16; ++j) { mybins[j] = h[base + j]; loc += mybins[j]; }

    __shared__ int suf[256];
    suf[t] = loc;
    __syncthreads();
    // inclusive suffix-sum over chunks: suf[t] = sum_{t'>=t} loc[t']
    for (int off = 1; off < 256; off <<= 1) {
        int add = (t + off < 256) ? suf[t + off] : 0;
        __syncthreads();
        suf[t] += add;
        __syncthreads();
    }
    int total = suf[0];

    int sel;
    if (which == 0) {
        sel = total < 256 ? total : 256;            // min(k=256, cl=256, #fg)
    } else {
        float nfg = nfg_sum[b];
        float cl  = 1024.f - fminf(nfg, 256.f);     // num_samp_bg (float)
        int cnt = (cl <= 0.f) ? 0 : (int)ceilf(cl); // #{j in [0,1024): j < cl}
        cnt = cnt > 1024 ? 1024 : cnt;
        sel = cnt < total ? cnt : total;
    }

    if (sel <= 0)      { if (t == 0) { bb[wb] = -1; rsel[wb] = 0; } return; }
    if (sel >= total)  { if (t == 0) { bb[wb] = -2; rsel[wb] = 0; } return; }

    int cumAbove = suf[t] - loc;                    // count in chunks above t
    if (cumAbove < sel && suf[t] >= sel) {          // boundary within my chunk
        int cum = cumAbove;
        for (int j = 15; j >= 0; --j) {
            cum += mybins[j];
            if (cum >= sel) {
                bb[wb]   = base + j;
                rsel[wb] = sel - (cum - mybins[j]); // 1-based rank within bin
                break;
            }
        }
    }
}

// K3: gather boundary-bin candidates
__global__ __launch_bounds__(256) void k3_gather(
    const unsigned* __restrict__ rec, const int* __restrict__ bb,
    unsigned long long* __restrict__ gbuf, int* __restrict__ gcnt)
{
    int g  = blockIdx.x * blockDim.x + threadIdx.x;
    int i0 = g << 2;
    int b  = i0 >> 18;
    int bbf = bb[b];
    int bbb = bb[32 + b];
    uint4 r = *reinterpret_cast<const uint4*>(rec + i0);
    #pragma unroll
    for (int j = 0; j < 4; ++j) {
        unsigned rv = ((const unsigned*)&r)[j];
        unsigned flag = rv >> 30;
        if (!flag) continue;
        unsigned ub = rv & 0x3FFFFFFFu;
        float u = __uint_as_float(ub);
        int bin = (int)(u * 4096.f);            // identical expr to K1 -> consistent
        bin = bin > (NBINS - 1) ? (NBINS - 1) : bin;
        int tgt = (flag == 1u) ? bbf : bbb;
        if (bin == tgt) {
            int wb = ((int)flag - 1) * 32 + b;
            int pos = atomicAdd(gcnt + wb, 1);
            if (pos < CAP) {
                unsigned inb = (unsigned)((i0 + j) & (TT - 1));
                gbuf[(size_t)wb * CAP + pos] =
                    ((unsigned long long)ub << 32) | (0xFFFFFFFFu - inb);
            }
        }
    }
}

// K4: exact r-th largest key among boundary-bin candidates
__global__ __launch_bounds__(256) void k4_thresh(
    const unsigned long long* __restrict__ gbuf, const int* __restrict__ gcnt,
    const int* __restrict__ bb, const int* __restrict__ rsel,
    unsigned long long* __restrict__ thr)
{
    int wb = blockIdx.x, t = threadIdx.x;
    int bbv = bb[wb];
    if (bbv == -1) { if (t == 0) thr[wb] = ~0ULL; return; }  // select none (keys < ~0)
    if (bbv == -2) { if (t == 0) thr[wb] = 0ULL;  return; }  // select all masked
    int n = gcnt[wb]; n = n > CAP ? CAP : n;
    int r = rsel[wb];
    const unsigned long long* buf = gbuf + (size_t)wb * CAP;
    for (int i = t; i < n; i += 256) {
        unsigned long long k = buf[i];
        int rank = 0;
        for (int j = 0; j < n; ++j) rank += (buf[j] > k) ? 1 : 0;
        if (rank == r - 1) thr[wb] = k;   // keys unique -> exactly one writer
    }
}

// K5: final anchor_valid write (in-place over rec: read uint4, store float4)
__global__ __launch_bounds__(256) void k5_anchor(
    unsigned* __restrict__ rec, const unsigned long long* __restrict__ thr)
{
    int g  = blockIdx.x * blockDim.x + threadIdx.x;
    int i0 = g << 2;
    int b  = i0 >> 18;
    unsigned long long tf = thr[b], tb = thr[32 + b];
    uint4 r = *reinterpret_cast<const uint4*>(rec + i0);
    float4 o;
    #pragma unroll
    for (int j = 0; j < 4; ++j) {
        unsigned rv = ((const unsigned*)&r)[j];
        unsigned flag = rv >> 30;
        float v = 0.f;
        if (flag) {
            unsigned ub  = rv & 0x3FFFFFFFu;
            unsigned inb = (unsigned)((i0 + j) & (TT - 1));
            unsigned long long key =
                ((unsigned long long)ub << 32) | (0xFFFFFFFFu - inb);
            v = (key >= ((flag == 1u) ? tf : tb)) ? 1.f : 0.f;
        }
        ((float*)&o)[j] = v;
    }
    *reinterpret_cast<float4*>(rec + i0) = o;   // same addresses, now floats
}

extern "C" void kernel_launch(void* const* d_in, const int* in_sizes, int n_in,
                              void* d_out, int out_size, void* d_ws, size_t ws_size,
                              hipStream_t stream)
{
    const float* gt   = (const float*)d_in[0];
    const float* alli = (const float*)d_in[1];
    const float* ufg  = (const float*)d_in[2];
    const float* ubg  = (const float*)d_in[3];

    char* ws = (char*)d_ws;
    int*                 hist = (int*)(ws + OFF_HIST);
    float*               nfg  = (float*)(ws + OFF_NFG);
    int*                 gcnt = (int*)(ws + OFF_GCNT);
    int*                 bb   = (int*)(ws + OFF_BB);
    int*                 rsel = (int*)(ws + OFF_RSEL);
    unsigned long long*  thr  = (unsigned long long*)(ws + OFF_THR);
    unsigned long long*  gbuf = (unsigned long long*)(ws + OFF_GBUF);

    float* coords = (float*)d_out;
    float* anchorF = coords + (size_t)3 * NCELL;     // final anchor_valid floats
    float* posv    = anchorF + NCELL;
    unsigned* rec  = (unsigned*)anchorF;             // K1..K5 staging, in-place

    hipMemsetAsync(d_ws, 0, ZERO_BYTES, stream);

    dim3 blk(256);
    dim3 grd(NCELL / 4 / 256);   // 8192 blocks
    k1_main<<<grd, blk, 0, stream>>>(gt, alli, ufg, ubg, coords, posv, rec, hist, nfg);
    k2_bounds<<<dim3(64), blk, 0, stream>>>(hist, nfg, bb, rsel);
    k3_gather<<<grd, blk, 0, stream>>>(rec, bb, gbuf, gcnt);
    k4_thresh<<<dim3(64), blk, 0, stream>>>(gbuf, gcnt, bb, rsel, thr);
    k5_anchor<<<grd, blk, 0, stream>>>(rec, thr);
}

// Round 10
// 525.479 us; speedup vs baseline: 1.1042x; 1.1042x over previous
//
#include <hip/hip_runtime.h>

// Problem constants
#define B_    32
#define T_    512
#define TT    (T_ * T_)        // 262144
#define NCELL (B_ * TT)        // 8388608
#define NBINS 256              // bin = floor(u*256): pow-2 scale, exact in fp32
#define CAP   8192

// Workspace layout (bytes) — total need: 5 MiB
#define OFF_HIST   0                            // int hist[2][32][256] = 64 KiB
#define OFF_NFG    (2 * B_ * NBINS * 4)         // float nfg_sum[32]
#define OFF_GCNT   (OFF_NFG + B_ * 4)           // int gcnt[64]
#define OFF_BB     (OFF_GCNT + 64 * 4)          // int bb[64]
#define OFF_RSEL   (OFF_BB + 64 * 4)            // int rsel[64]
#define OFF_THR    (OFF_RSEL + 64 * 4)          // u64 thr[64] (66432 -> 8B aligned)
#define ZERO_BYTES (OFF_THR + 64 * 8)
#define OFF_GBUF   (1u * 1024 * 1024)           // u64 gbuf[64][CAP] = 4 MiB
// rec[NCELL] (packed flag|u_bits) lives in d_out's anchor region:
// written by K1, read by K3, read+overwritten in place by K5.

// K1: block = 8192 cells of one batch. LDS-privatized histogram (flush
// <=512 global atomics/block instead of 8192), coalesced stripe writer
// for coords (pure function of index, lane-contiguous float4 stores).
__global__ __launch_bounds__(256) void k1_main(
    const float* __restrict__ gt, const float* __restrict__ alli,
    const float* __restrict__ ufg, const float* __restrict__ ubg,
    float* __restrict__ coords, float* __restrict__ posv,
    unsigned* __restrict__ rec, int* __restrict__ hist,
    float* __restrict__ nfg_sum)
{
    __shared__ int lh[2][NBINS];
    int tid = threadIdx.x;
    lh[0][tid] = 0;
    lh[1][tid] = 0;
    __syncthreads();

    int bid  = blockIdx.x;
    int b    = bid >> 5;                   // 32 blocks per batch
    int base = b * TT + (bid & 31) * 8192;

    float fgsum = 0.f;
    #pragma unroll
    for (int it = 0; it < 8; ++it) {
        int i0 = base + it * 1024 + tid * 4;
        float4 gv = *reinterpret_cast<const float4*>(gt   + i0);
        float4 av = *reinterpret_cast<const float4*>(alli + i0);
        float4 fv = *reinterpret_cast<const float4*>(ufg  + i0);
        float4 bv = *reinterpret_cast<const float4*>(ubg  + i0);
        float4 pv; uint4 rv;
        #pragma unroll
        for (int j = 0; j < 4; ++j) {
            float gtv = ((const float*)&gv)[j];
            float al  = ((const float*)&av)[j];
            bool  fgc   = (gtv > 0.5f);
            float fgval = fgc ? al : 0.f;
            fgsum += fgval;
            bool fg = fgval > 0.f;
            bool bg = (!fgc) && (al > 0.f);
            ((float*)&pv)[j] = (fgc && al >= 1.f) ? 1.f : 0.f;
            unsigned flag = fg ? 1u : (bg ? 2u : 0u);
            unsigned out  = 0u;
            if (flag) {
                float u = (flag == 1u) ? ((const float*)&fv)[j] : ((const float*)&bv)[j];
                unsigned ub = __float_as_uint(u);   // u in [0,1) -> fits 30 bits
                out = (flag << 30) | ub;
                int bin = (int)(u * 256.f);         // exact pow2 scale
                bin = bin > (NBINS - 1) ? (NBINS - 1) : bin;
                atomicAdd(&lh[flag - 1][bin], 1);   // LDS atomic (cheap)
            }
            ((unsigned*)&rv)[j] = out;
        }
        *reinterpret_cast<float4*>(posv + i0) = pv;
        *reinterpret_cast<uint4*>(rec + i0)   = rv;
    }
    __syncthreads();

    // flush block-local histogram: <=512 global atomics per block
    int v0 = lh[0][tid];
    if (v0) atomicAdd(hist + b * NBINS + tid, v0);
    int v1 = lh[1][tid];
    if (v1) atomicAdd(hist + (B_ + b) * NBINS + tid, v1);

    // fg-mask value sum: wave reduce then block reduce, one atomic per block
    for (int off = 32; off; off >>= 1) fgsum += __shfl_down(fgsum, off);
    __shared__ float red[4];
    int lane = tid & 63, w = tid >> 6;
    if (lane == 0) red[w] = fgsum;
    __syncthreads();
    if (tid == 0) {
        float t = red[0] + red[1] + red[2] + red[3];
        if (t != 0.f) atomicAdd(nfg_sum + b, t);
    }

    // coords: grid-strided contiguous float4 stripes (fully coalesced).
    // float index p -> cell i = p/3, comp c = p%3; row i = [b, s, s+d+1].
    unsigned g = (unsigned)bid * 256u + (unsigned)tid;   // 262144 threads
    #pragma unroll
    for (int k = 0; k < 24; ++k) {                       // 24*262144 float4s
        unsigned q  = (unsigned)k * 262144u + g;         // float4 index
        unsigned p0 = q * 4u;                            // float index
        float4 o;
        #pragma unroll
        for (int j = 0; j < 4; ++j) {
            unsigned p  = p0 + (unsigned)j;
            unsigned i  = p / 3u;                        // magic-mul div
            unsigned c  = p - i * 3u;
            unsigned ib = i >> 18;
            unsigned rm = i & (TT - 1);
            unsigned s  = rm & (T_ - 1);
            unsigned e  = (rm >> 9) + s + 1u;
            unsigned v  = (c == 0u) ? ib : ((c == 1u) ? s : e);
            ((float*)&o)[j] = (float)v;
        }
        reinterpret_cast<float4*>(coords)[q] = o;
    }
}

// K2: per (which,b): one thread per bin, suffix-scan, boundary bin + rank
__global__ __launch_bounds__(256) void k2_bounds(
    const int* __restrict__ hist, const float* __restrict__ nfg_sum,
    int* __restrict__ bb, int* __restrict__ rsel)
{
    int wb = blockIdx.x;              // 0..63: which*32 + b
    int which = wb >> 5, b = wb & 31;
    const int* h = hist + wb * NBINS;
    int t = threadIdx.x;
    int mybin = h[t];

    __shared__ int suf[256];
    suf[t] = mybin;
    __syncthreads();
    // inclusive suffix-sum: suf[t] = sum_{t'>=t} h[t']
    for (int off = 1; off < 256; off <<= 1) {
        int add = (t + off < 256) ? suf[t + off] : 0;
        __syncthreads();
        suf[t] += add;
        __syncthreads();
    }
    int total = suf[0];

    int sel;
    if (which == 0) {
        sel = total < 256 ? total : 256;            // min(k=256, cl=256, #fg)
    } else {
        float nfg = nfg_sum[b];
        float cl  = 1024.f - fminf(nfg, 256.f);     // num_samp_bg (float)
        int cnt = (cl <= 0.f) ? 0 : (int)ceilf(cl); // #{j in [0,1024): j < cl}
        cnt = cnt > 1024 ? 1024 : cnt;
        sel = cnt < total ? cnt : total;
    }

    if (sel <= 0)      { if (t == 0) { bb[wb] = -1; rsel[wb] = 0; } return; }
    if (sel >= total)  { if (t == 0) { bb[wb] = -2; rsel[wb] = 0; } return; }

    int cumAbove = suf[t] - mybin;                  // cells in bins above t
    if (cumAbove < sel && suf[t] >= sel) {          // unique boundary thread
        bb[wb]   = t;
        rsel[wb] = sel - cumAbove;                  // 1-based rank within bin
    }
}

// K3: gather boundary-bin candidates (~512 per (which,b))
__global__ __launch_bounds__(256) void k3_gather(
    const unsigned* __restrict__ rec, const int* __restrict__ bb,
    unsigned long long* __restrict__ gbuf, int* __restrict__ gcnt)
{
    int g  = blockIdx.x * blockDim.x + threadIdx.x;
    int i0 = g << 2;
    int b  = i0 >> 18;
    int bbf = bb[b];
    int bbb = bb[32 + b];
    uint4 r = *reinterpret_cast<const uint4*>(rec + i0);
    #pragma unroll
    for (int j = 0; j < 4; ++j) {
        unsigned rv = ((const unsigned*)&r)[j];
        unsigned flag = rv >> 30;
        if (!flag) continue;
        unsigned ub = rv & 0x3FFFFFFFu;
        float u = __uint_as_float(ub);
        int bin = (int)(u * 256.f);             // identical expr to K1
        bin = bin > (NBINS - 1) ? (NBINS - 1) : bin;
        int tgt = (flag == 1u) ? bbf : bbb;
        if (bin == tgt) {
            int wb = ((int)flag - 1) * 32 + b;
            int pos = atomicAdd(gcnt + wb, 1);
            if (pos < CAP) {
                unsigned inb = (unsigned)((i0 + j) & (TT - 1));
                gbuf[(size_t)wb * CAP + pos] =
                    ((unsigned long long)ub << 32) | (0xFFFFFFFFu - inb);
            }
        }
    }
}

// K4: exact r-th largest key among boundary-bin candidates
__global__ __launch_bounds__(256) void k4_thresh(
    const unsigned long long* __restrict__ gbuf, const int* __restrict__ gcnt,
    const int* __restrict__ bb, const int* __restrict__ rsel,
    unsigned long long* __restrict__ thr)
{
    int wb = blockIdx.x, t = threadIdx.x;
    int bbv = bb[wb];
    if (bbv == -1) { if (t == 0) thr[wb] = ~0ULL; return; }  // select none
    if (bbv == -2) { if (t == 0) thr[wb] = 0ULL;  return; }  // select all masked
    int n = gcnt[wb]; n = n > CAP ? CAP : n;
    int r = rsel[wb];
    const unsigned long long* buf = gbuf + (size_t)wb * CAP;
    for (int i = t; i < n; i += 256) {
        unsigned long long k = buf[i];
        int rank = 0;
        for (int j = 0; j < n; ++j) rank += (buf[j] > k) ? 1 : 0;
        if (rank == r - 1) thr[wb] = k;   // keys unique -> exactly one writer
    }
}

// K5: final anchor_valid write (in-place over rec: read uint4, store float4)
__global__ __launch_bounds__(256) void k5_anchor(
    unsigned* __restrict__ rec, const unsigned long long* __restrict__ thr)
{
    int g  = blockIdx.x * blockDim.x + threadIdx.x;
    int i0 = g << 2;
    int b  = i0 >> 18;
    unsigned long long tf = thr[b], tb = thr[32 + b];
    uint4 r = *reinterpret_cast<const uint4*>(rec + i0);
    float4 o;
    #pragma unroll
    for (int j = 0; j < 4; ++j) {
        unsigned rv = ((const unsigned*)&r)[j];
        unsigned flag = rv >> 30;
        float v = 0.f;
        if (flag) {
            unsigned ub  = rv & 0x3FFFFFFFu;
            unsigned inb = (unsigned)((i0 + j) & (TT - 1));
            unsigned long long key =
                ((unsigned long long)ub << 32) | (0xFFFFFFFFu - inb);
            v = (key >= ((flag == 1u) ? tf : tb)) ? 1.f : 0.f;
        }
        ((float*)&o)[j] = v;
    }
    *reinterpret_cast<float4*>(rec + i0) = o;   // same addresses, now floats
}

extern "C" void kernel_launch(void* const* d_in, const int* in_sizes, int n_in,
                              void* d_out, int out_size, void* d_ws, size_t ws_size,
                              hipStream_t stream)
{
    const float* gt   = (const float*)d_in[0];
    const float* alli = (const float*)d_in[1];
    const float* ufg  = (const float*)d_in[2];
    const float* ubg  = (const float*)d_in[3];

    char* ws = (char*)d_ws;
    int*                 hist = (int*)(ws + OFF_HIST);
    float*               nfg  = (float*)(ws + OFF_NFG);
    int*                 gcnt = (int*)(ws + OFF_GCNT);
    int*                 bb   = (int*)(ws + OFF_BB);
    int*                 rsel = (int*)(ws + OFF_RSEL);
    unsigned long long*  thr  = (unsigned long long*)(ws + OFF_THR);
    unsigned long long*  gbuf = (unsigned long long*)(ws + OFF_GBUF);

    float* coords  = (float*)d_out;
    float* anchorF = coords + (size_t)3 * NCELL;     // final anchor_valid floats
    unsigned* rec  = (unsigned*)anchorF;             // staging, overwritten by K5
    float* posv    = anchorF + NCELL;

    hipMemsetAsync(d_ws, 0, ZERO_BYTES, stream);

    dim3 blk(256);
    k1_main<<<dim3(1024), blk, 0, stream>>>(gt, alli, ufg, ubg, coords, posv, rec, hist, nfg);
    k2_bounds<<<dim3(64), blk, 0, stream>>>(hist, nfg, bb, rsel);
    k3_gather<<<dim3(8192), blk, 0, stream>>>(rec, bb, gbuf, gcnt);
    k4_thresh<<<dim3(64), blk, 0, stream>>>(gbuf, gcnt, bb, rsel, thr);
    k5_anchor<<<dim3(8192), blk, 0, stream>>>(rec, thr);
}

// Round 11
// 368.247 us; speedup vs baseline: 1.5756x; 1.4270x over previous
//
#include <hip/hip_runtime.h>

// Problem constants
#define B_    32
#define T_    512
#define TT    (T_ * T_)        // 262144
#define NCELL (B_ * TT)        // 8388608
#define NBINS 256              // bin = floor(u*256): pow-2 scale, exact in fp32
#define CAP   8192

// Workspace layout (bytes) — total need: 5 MiB
#define OFF_HIST   0                            // int hist[2][32][256] = 64 KiB
#define OFF_NFG    (2 * B_ * NBINS * 4)         // float nfg_sum[32]
#define OFF_GCNT   (OFF_NFG + B_ * 4)           // int gcnt[64]
#define OFF_BB     (OFF_GCNT + 64 * 4)          // int bb[64]
#define OFF_RSEL   (OFF_BB + 64 * 4)            // int rsel[64]
#define OFF_THR    (OFF_RSEL + 64 * 4)          // u64 thr[64] (66432 -> 8B aligned)
#define ZERO_BYTES (OFF_THR + 64 * 8)
#define OFF_GBUF   (1u * 1024 * 1024)           // u64 gbuf[64][CAP] = 4 MiB
// rec[NCELL] (packed flag|u_bits) lives in d_out's anchor region:
// written by K1, read by K3, read+overwritten in place by K5.

// K1: block = 8192 cells of one batch. LDS-privatized histogram (flush
// <=512 global atomics/block instead of 8192), coalesced stripe writer
// for coords (pure function of index, lane-contiguous float4 stores).
__global__ __launch_bounds__(256) void k1_main(
    const float* __restrict__ gt, const float* __restrict__ alli,
    const float* __restrict__ ufg, const float* __restrict__ ubg,
    float* __restrict__ coords, float* __restrict__ posv,
    unsigned* __restrict__ rec, int* __restrict__ hist,
    float* __restrict__ nfg_sum)
{
    __shared__ int lh[2][NBINS];
    int tid = threadIdx.x;
    lh[0][tid] = 0;
    lh[1][tid] = 0;
    __syncthreads();

    int bid  = blockIdx.x;
    int b    = bid >> 5;                   // 32 blocks per batch
    int base = b * TT + (bid & 31) * 8192;

    float fgsum = 0.f;
    #pragma unroll
    for (int it = 0; it < 8; ++it) {
        int i0 = base + it * 1024 + tid * 4;
        float4 gv = *reinterpret_cast<const float4*>(gt   + i0);
        float4 av = *reinterpret_cast<const float4*>(alli + i0);
        float4 fv = *reinterpret_cast<const float4*>(ufg  + i0);
        float4 bv = *reinterpret_cast<const float4*>(ubg  + i0);
        float4 pv; uint4 rv;
        #pragma unroll
        for (int j = 0; j < 4; ++j) {
            float gtv = ((const float*)&gv)[j];
            float al  = ((const float*)&av)[j];
            bool  fgc   = (gtv > 0.5f);
            float fgval = fgc ? al : 0.f;
            fgsum += fgval;
            bool fg = fgval > 0.f;
            bool bg = (!fgc) && (al > 0.f);
            ((float*)&pv)[j] = (fgc && al >= 1.f) ? 1.f : 0.f;
            unsigned flag = fg ? 1u : (bg ? 2u : 0u);
            unsigned out  = 0u;
            if (flag) {
                float u = (flag == 1u) ? ((const float*)&fv)[j] : ((const float*)&bv)[j];
                unsigned ub = __float_as_uint(u);   // u in [0,1) -> fits 30 bits
                out = (flag << 30) | ub;
                int bin = (int)(u * 256.f);         // exact pow2 scale
                bin = bin > (NBINS - 1) ? (NBINS - 1) : bin;
                atomicAdd(&lh[flag - 1][bin], 1);   // LDS atomic (cheap)
            }
            ((unsigned*)&rv)[j] = out;
        }
        *reinterpret_cast<float4*>(posv + i0) = pv;
        *reinterpret_cast<uint4*>(rec + i0)   = rv;
    }
    __syncthreads();

    // flush block-local histogram: <=512 global atomics per block
    int v0 = lh[0][tid];
    if (v0) atomicAdd(hist + b * NBINS + tid, v0);
    int v1 = lh[1][tid];
    if (v1) atomicAdd(hist + (B_ + b) * NBINS + tid, v1);

    // fg-mask value sum: wave reduce then block reduce, one atomic per block
    for (int off = 32; off; off >>= 1) fgsum += __shfl_down(fgsum, off);
    __shared__ float red[4];
    int lane = tid & 63, w = tid >> 6;
    if (lane == 0) red[w] = fgsum;
    __syncthreads();
    if (tid == 0) {
        float t = red[0] + red[1] + red[2] + red[3];
        if (t != 0.f) atomicAdd(nfg_sum + b, t);
    }

    // coords: grid-strided contiguous float4 stripes (fully coalesced).
    // float index p -> cell i = p/3, comp c = p%3; row i = [b, s, s+d+1].
    unsigned g = (unsigned)bid * 256u + (unsigned)tid;   // 262144 threads
    #pragma unroll
    for (int k = 0; k < 24; ++k) {                       // 24*262144 float4s
        unsigned q  = (unsigned)k * 262144u + g;         // float4 index
        unsigned p0 = q * 4u;                            // float index
        float4 o;
        #pragma unroll
        for (int j = 0; j < 4; ++j) {
            unsigned p  = p0 + (unsigned)j;
            unsigned i  = p / 3u;                        // magic-mul div
            unsigned c  = p - i * 3u;
            unsigned ib = i >> 18;
            unsigned rm = i & (TT - 1);
            unsigned s  = rm & (T_ - 1);
            unsigned e  = (rm >> 9) + s + 1u;
            unsigned v  = (c == 0u) ? ib : ((c == 1u) ? s : e);
            ((float*)&o)[j] = (float)v;
        }
        reinterpret_cast<float4*>(coords)[q] = o;
    }
}

// K2: per (which,b): one thread per bin, suffix-scan, boundary bin + rank
__global__ __launch_bounds__(256) void k2_bounds(
    const int* __restrict__ hist, const float* __restrict__ nfg_sum,
    int* __restrict__ bb, int* __restrict__ rsel)
{
    int wb = blockIdx.x;              // 0..63: which*32 + b
    int which = wb >> 5, b = wb & 31;
    const int* h = hist + wb * NBINS;
    int t = threadIdx.x;
    int mybin = h[t];

    __shared__ int suf[256];
    suf[t] = mybin;
    __syncthreads();
    // inclusive suffix-sum: suf[t] = sum_{t'>=t} h[t']
    for (int off = 1; off < 256; off <<= 1) {
        int add = (t + off < 256) ? suf[t + off] : 0;
        __syncthreads();
        suf[t] += add;
        __syncthreads();
    }
    int total = suf[0];

    int sel;
    if (which == 0) {
        sel = total < 256 ? total : 256;            // min(k=256, cl=256, #fg)
    } else {
        float nfg = nfg_sum[b];
        float cl  = 1024.f - fminf(nfg, 256.f);     // num_samp_bg (float)
        int cnt = (cl <= 0.f) ? 0 : (int)ceilf(cl); // #{j in [0,1024): j < cl}
        cnt = cnt > 1024 ? 1024 : cnt;
        sel = cnt < total ? cnt : total;
    }

    if (sel <= 0)      { if (t == 0) { bb[wb] = -1; rsel[wb] = 0; } return; }
    if (sel >= total)  { if (t == 0) { bb[wb] = -2; rsel[wb] = 0; } return; }

    int cumAbove = suf[t] - mybin;                  // cells in bins above t
    if (cumAbove < sel && suf[t] >= sel) {          // unique boundary thread
        bb[wb]   = t;
        rsel[wb] = sel - cumAbove;                  // 1-based rank within bin
    }
}

// K3: gather boundary-bin candidates. Block = 8192 cells of one batch.
// Candidates held in 2 named register slots/thread (expected 0.25),
// counted in LDS, then ONE global atomicAdd per (block,which) reserves a
// contiguous gbuf range -> 2048 contended atomics total instead of ~32K
// returning atomics on 64 hot counters (R10: 178us @ 1.3% HBM / 1.6% VALU
// was pure atomic-serialization stall). Overflow (>2/thread, P~1e-12 for
// uniform input) falls back to the direct-atomic path for correctness.
__global__ __launch_bounds__(256) void k3_gather(
    const unsigned* __restrict__ rec, const int* __restrict__ bb,
    unsigned long long* __restrict__ gbuf, int* __restrict__ gcnt)
{
    __shared__ int lcnt[2];
    __shared__ int lpos[2];
    __shared__ int lbase[2];
    int tid = threadIdx.x;
    if (tid < 2) { lcnt[tid] = 0; lpos[tid] = 0; }
    __syncthreads();

    int bid  = blockIdx.x;
    int b    = bid >> 5;                   // 32 blocks per batch
    int base = b * TT + (bid & 31) * 8192;
    int bbf = bb[b];
    int bbb = bb[32 + b];

    unsigned long long c0 = 0, c1 = 0;
    int w0 = 0, w1 = 0, mycnt = 0;

    #pragma unroll
    for (int it = 0; it < 8; ++it) {
        int i0 = base + it * 1024 + tid * 4;
        uint4 r = *reinterpret_cast<const uint4*>(rec + i0);
        #pragma unroll
        for (int j = 0; j < 4; ++j) {
            unsigned rv = ((const unsigned*)&r)[j];
            unsigned flag = rv >> 30;
            if (!flag) continue;
            unsigned ub = rv & 0x3FFFFFFFu;
            float u = __uint_as_float(ub);
            int bin = (int)(u * 256.f);         // identical expr to K1
            bin = bin > (NBINS - 1) ? (NBINS - 1) : bin;
            int w = (int)flag - 1;
            if (bin == ((w == 0) ? bbf : bbb)) {
                unsigned inb = (unsigned)((i0 + j) & (TT - 1));
                unsigned long long key =
                    ((unsigned long long)ub << 32) | (0xFFFFFFFFu - inb);
                if (mycnt == 0)      { c0 = key; w0 = w; mycnt = 1; atomicAdd(&lcnt[w], 1); }
                else if (mycnt == 1) { c1 = key; w1 = w; mycnt = 2; atomicAdd(&lcnt[w], 1); }
                else {
                    // vanishingly rare overflow: direct global reservation
                    int wb = w * 32 + b;
                    int pos = atomicAdd(gcnt + wb, 1);
                    if (pos < CAP) gbuf[(size_t)wb * CAP + pos] = key;
                }
            }
        }
    }
    __syncthreads();

    // one returning global atomic per (block, which)
    if (tid == 0) lbase[0] = lcnt[0] ? atomicAdd(gcnt + b, lcnt[0]) : 0;
    if (tid == 1) lbase[1] = lcnt[1] ? atomicAdd(gcnt + 32 + b, lcnt[1]) : 0;
    __syncthreads();

    if (mycnt >= 1) {
        int ofs = atomicAdd(&lpos[w0], 1);
        int p = lbase[w0] + ofs;
        if (p < CAP) gbuf[(size_t)(w0 * 32 + b) * CAP + p] = c0;
    }
    if (mycnt >= 2) {
        int ofs = atomicAdd(&lpos[w1], 1);
        int p = lbase[w1] + ofs;
        if (p < CAP) gbuf[(size_t)(w1 * 32 + b) * CAP + p] = c1;
    }
}

// K4: exact r-th largest key among boundary-bin candidates
__global__ __launch_bounds__(256) void k4_thresh(
    const unsigned long long* __restrict__ gbuf, const int* __restrict__ gcnt,
    const int* __restrict__ bb, const int* __restrict__ rsel,
    unsigned long long* __restrict__ thr)
{
    int wb = blockIdx.x, t = threadIdx.x;
    int bbv = bb[wb];
    if (bbv == -1) { if (t == 0) thr[wb] = ~0ULL; return; }  // select none
    if (bbv == -2) { if (t == 0) thr[wb] = 0ULL;  return; }  // select all masked
    int n = gcnt[wb]; n = n > CAP ? CAP : n;
    int r = rsel[wb];
    const unsigned long long* buf = gbuf + (size_t)wb * CAP;
    for (int i = t; i < n; i += 256) {
        unsigned long long k = buf[i];
        int rank = 0;
        for (int j = 0; j < n; ++j) rank += (buf[j] > k) ? 1 : 0;
        if (rank == r - 1) thr[wb] = k;   // keys unique -> exactly one writer
    }
}

// K5: final anchor_valid write (in-place over rec: read uint4, store float4)
__global__ __launch_bounds__(256) void k5_anchor(
    unsigned* __restrict__ rec, const unsigned long long* __restrict__ thr)
{
    int g  = blockIdx.x * blockDim.x + threadIdx.x;
    int i0 = g << 2;
    int b  = i0 >> 18;
    unsigned long long tf = thr[b], tb = thr[32 + b];
    uint4 r = *reinterpret_cast<const uint4*>(rec + i0);
    float4 o;
    #pragma unroll
    for (int j = 0; j < 4; ++j) {
        unsigned rv = ((const unsigned*)&r)[j];
        unsigned flag = rv >> 30;
        float v = 0.f;
        if (flag) {
            unsigned ub  = rv & 0x3FFFFFFFu;
            unsigned inb = (unsigned)((i0 + j) & (TT - 1));
            unsigned long long key =
                ((unsigned long long)ub << 32) | (0xFFFFFFFFu - inb);
            v = (key >= ((flag == 1u) ? tf : tb)) ? 1.f : 0.f;
        }
        ((float*)&o)[j] = v;
    }
    *reinterpret_cast<float4*>(rec + i0) = o;   // same addresses, now floats
}

extern "C" void kernel_launch(void* const* d_in, const int* in_sizes, int n_in,
                              void* d_out, int out_size, void* d_ws, size_t ws_size,
                              hipStream_t stream)
{
    const float* gt   = (const float*)d_in[0];
    const float* alli = (const float*)d_in[1];
    const float* ufg  = (const float*)d_in[2];
    const float* ubg  = (const float*)d_in[3];

    char* ws = (char*)d_ws;
    int*                 hist = (int*)(ws + OFF_HIST);
    float*               nfg  = (float*)(ws + OFF_NFG);
    int*                 gcnt = (int*)(ws + OFF_GCNT);
    int*                 bb   = (int*)(ws + OFF_BB);
    int*                 rsel = (int*)(ws + OFF_RSEL);
    unsigned long long*  thr  = (unsigned long long*)(ws + OFF_THR);
    unsigned long long*  gbuf = (unsigned long long*)(ws + OFF_GBUF);

    float* coords  = (float*)d_out;
    float* anchorF = coords + (size_t)3 * NCELL;     // final anchor_valid floats
    unsigned* rec  = (unsigned*)anchorF;             // staging, overwritten by K5
    float* posv    = anchorF + NCELL;

    hipMemsetAsync(d_ws, 0, ZERO_BYTES, stream);

    dim3 blk(256);
    k1_main<<<dim3(1024), blk, 0, stream>>>(gt, alli, ufg, ubg, coords, posv, rec, hist, nfg);
    k2_bounds<<<dim3(64), blk, 0, stream>>>(hist, nfg, bb, rsel);
    k3_gather<<<dim3(1024), blk, 0, stream>>>(rec, bb, gbuf, gcnt);
    k4_thresh<<<dim3(64), blk, 0, stream>>>(gbuf, gcnt, bb, rsel, thr);
    k5_anchor<<<dim3(8192), blk, 0, stream>>>(rec, thr);
}